// Round 20
// baseline (134.333 us; speedup 1.0000x reference)
//
#include <hip/hip_runtime.h>
#include <hip/hip_bf16.h>

#define BATCH 8
#define NPT   2048
#define DIM   512
#define NTILE 16            // 2048/128 tiles per dim
#define NTRI  136           // 16*17/2 symmetric tiles per batch
#define NBLK  (NTRI * BATCH) // 1088

typedef __attribute__((ext_vector_type(4))) float f32x4;
typedef __attribute__((ext_vector_type(4))) int   i32x4;
typedef __attribute__((ext_vector_type(8))) int   i32x8;

// ---------------- workspace layout ----------------
// xn (fp8)  : 8,388,608 B at 0
#define OFF_SQ       16777216
#define OFF_MSUM     16842752
#define OFF_PARTIALS 16842784   // 1088 floats

// ---------------- kernel 1: normalize rows, emit fp8 e4m3 + per-row |x_q|^2 ----------------
__global__ __launch_bounds__(256) void normalize_kernel(const float* __restrict__ emb,
                                                        unsigned char* __restrict__ xn,
                                                        float* __restrict__ sq) {
    const int wave = threadIdx.x >> 6;
    const int lane = threadIdx.x & 63;
    const int row  = blockIdx.x * 4 + wave;

    const float4* src = (const float4*)(emb + (size_t)row * DIM);
    float4 v0 = src[lane * 2 + 0];
    float4 v1 = src[lane * 2 + 1];

    float ss = v0.x*v0.x + v0.y*v0.y + v0.z*v0.z + v0.w*v0.w
             + v1.x*v1.x + v1.y*v1.y + v1.z*v1.z + v1.w*v1.w;
#pragma unroll
    for (int o = 32; o; o >>= 1) ss += __shfl_xor(ss, o);

    const float inv = 1.0f / fmaxf(sqrtf(ss), 1e-12f);

    const float f0 = v0.x*inv, f1 = v0.y*inv, f2 = v0.z*inv, f3 = v0.w*inv;
    const float f4 = v1.x*inv, f5 = v1.y*inv, f6 = v1.z*inv, f7 = v1.w*inv;

    int lo = __builtin_amdgcn_cvt_pk_fp8_f32(f0, f1, 0, 0);
    lo     = __builtin_amdgcn_cvt_pk_fp8_f32(f2, f3, lo, 1);
    int hi = __builtin_amdgcn_cvt_pk_fp8_f32(f4, f5, 0, 0);
    hi     = __builtin_amdgcn_cvt_pk_fp8_f32(f6, f7, hi, 1);

    float s2 = 0.f;
    {
        float a;
        a = __builtin_amdgcn_cvt_f32_fp8(lo, 0); s2 += a * a;
        a = __builtin_amdgcn_cvt_f32_fp8(lo, 1); s2 += a * a;
        a = __builtin_amdgcn_cvt_f32_fp8(lo, 2); s2 += a * a;
        a = __builtin_amdgcn_cvt_f32_fp8(lo, 3); s2 += a * a;
        a = __builtin_amdgcn_cvt_f32_fp8(hi, 0); s2 += a * a;
        a = __builtin_amdgcn_cvt_f32_fp8(hi, 1); s2 += a * a;
        a = __builtin_amdgcn_cvt_f32_fp8(hi, 2); s2 += a * a;
        a = __builtin_amdgcn_cvt_f32_fp8(hi, 3); s2 += a * a;
    }

    uint2 pk; pk.x = (unsigned)lo; pk.y = (unsigned)hi;
    *(uint2*)(xn + (size_t)row * DIM + lane * 8) = pk;

#pragma unroll
    for (int o = 32; o; o >>= 1) s2 += __shfl_xor(s2, o);
    if (lane == 0) sq[row] = s2;
}

// ---------------- kernel 2: per-batch mask sums (8 parallel blocks) ----------------
// NOTE round 16: fusing this into finalize cost 13 us. Keep parallel.
__global__ __launch_bounds__(256) void masksum_kernel(const float* __restrict__ mask,
                                                      float* __restrict__ msum) {
    const int b = blockIdx.x;
    float s = 0.f;
    for (int i = threadIdx.x; i < NPT; i += 256) s += mask[b * NPT + i];
#pragma unroll
    for (int o = 32; o; o >>= 1) s += __shfl_xor(s, o);
    __shared__ float ws[4];
    if ((threadIdx.x & 63) == 0) ws[threadIdx.x >> 6] = s;
    __syncthreads();
    if (threadIdx.x == 0) msum[b] = ws[0] + ws[1] + ws[2] + ws[3];
}

// ---------------- kernel 3: MX-fp8 Gram, 128x128 tile, BK=128, FOUR phases ----------------
// Rendezvous-count round: mfma_scale_f32_16x16x128_f8f6f4 with UNIT scales
// (e8m0 0x7F = 2^0) packs K=128 per instruction at 2x fp8 rate (m21/m148) ->
// K=512 in 4 phases instead of 16, attacking the measured per-phase VMW+barrier
// cost directly. Unit scales = bit-identical math to rounds 12-19's fp8 path.
// A/B fragments load identically, so any within-lane k-permutation cancels in
// the Gram; C/D layout is shape-determined (m89-m128) -> epilogue unchanged.
// 8 waves x (64x32); per wave-phase 8 MFMA + 12 ds_read_b128.
// LDS: 2 buffers x 16 KB x 2 sides = 64 KB + meta -> 2 blocks/CU.
// Swizzle (128-B rows, 8 chunks): stored chunk c holds source chunk c^(row&7);
// read logical chunk (2*lhi+j) at phys (2*lhi+j)^(llo&7) -> per 16-lane group
// 8 chunk slots x 2 lanes = 2-way aliasing (free, m136).
__global__ __launch_bounds__(512, 4) void gram_loss_kernel(const unsigned char* __restrict__ xn,
                                                           const float* __restrict__ sq,
                                                           const float* __restrict__ coords,
                                                           const float* __restrict__ mask,
                                                           float* __restrict__ partials) {
    __shared__ __align__(16) unsigned char ldsA[2][16384];   // 32 KB
    __shared__ __align__(16) unsigned char ldsB[2][16384];   // 32 KB
    __shared__ float s_sqr[128], s_sqc[128], s_mr[128], s_mc[128];
    __shared__ float s_cr[128][3], s_cc[128][3];
    __shared__ float s_wsum[8];

    // XCD-chunked: 1088 = 8 * 136; batch == XCD id -> ~1 MB panel set per XCD L2
    const int bid = blockIdx.x;
    const int b   = bid & 7;
    int r = bid >> 3;
    int tm = 0;
    while (r >= NTILE - tm) { r -= NTILE - tm; tm++; }
    const int tn = tm + r;

    const int t    = threadIdx.x;
    const int wave = t >> 6, lane = t & 63;
    const int wr = wave >> 2, wc = wave & 3;      // 2 x 4 wave grid: 64-row x 32-col tiles
    const int lhi = lane >> 4, llo = lane & 15;

    const size_t rowBaseA = (size_t)(b * NPT + tm * 128);
    const size_t rowBaseB = (size_t)(b * NPT + tn * 128);

    f32x4 acc[4][2];
#pragma unroll
    for (int i = 0; i < 4; i++)
#pragma unroll
        for (int j = 0; j < 2; j++) acc[i][j] = (f32x4){0.f, 0.f, 0.f, 0.f};

    // ---- staging: region = 128 rows x 128 B = 16 KB/side = 1024 chunks of 16 B.
    // threads 0-255 stage A, 256-511 stage B; 4 chunks each: f = j*256 + ls.
    // chunk f: row = f>>3, phys = f&7, src = phys ^ (row&7); dst = f*16 (linear).
    const int ls   = t & 255;
    const int side = t >> 8;
    const unsigned char* panel = xn + (side ? rowBaseB : rowBaseA) * DIM;
    int goff[4], doff[4];
#pragma unroll
    for (int j = 0; j < 4; j++) {
        const int f   = j * 256 + ls;
        const int row = f >> 3;
        const int cs  = (f & 7) ^ (row & 7);
        goff[j] = row * DIM + cs * 16;
        doff[j] = f * 16;
    }

#define STAGE_REGION(q_)                                                                        \
    {                                                                                           \
        unsigned char* base_ = side ? &ldsB[(q_) & 1][0] : &ldsA[(q_) & 1][0];                  \
        _Pragma("unroll")                                                                       \
        for (int j = 0; j < 4; j++)                                                             \
            __builtin_amdgcn_global_load_lds(                                                   \
                (const __attribute__((address_space(1))) void*)(panel + goff[j] + (q_) * 128),  \
                (__attribute__((address_space(3))) void*)(base_ + doff[j]), 16, 0, 0);          \
    }

#define VMW(n_) asm volatile("s_waitcnt vmcnt(" #n_ ")" ::: "memory")

    STAGE_REGION(0);
    VMW(0);
    __builtin_amdgcn_s_barrier();

    // fragment reads: row byte = row*128; logical chunk c at phys (c ^ (llo&7))*16
    const int x7     = llo & 7;
    const int cA0    = ((2 * lhi + 0) ^ x7) * 16;
    const int cA1    = ((2 * lhi + 1) ^ x7) * 16;
    const int rowAby = (wr * 64 + llo) * 128;   // + mi*2048
    const int rowBby = (wc * 32 + llo) * 128;   // + ni*2048

#define PHASE(p_, dostage_)                                                                     \
    {                                                                                           \
        const unsigned char* baA = &ldsA[(p_) & 1][0];                                          \
        const unsigned char* baB = &ldsB[(p_) & 1][0];                                          \
        i32x8 af[4], bfr[2];                                                                    \
        _Pragma("unroll")                                                                       \
        for (int mi = 0; mi < 4; mi++) {                                                        \
            i32x4 lo_ = *(const i32x4*)(baA + rowAby + mi * 2048 + cA0);                        \
            i32x4 hi_ = *(const i32x4*)(baA + rowAby + mi * 2048 + cA1);                        \
            af[mi] = __builtin_shufflevector(lo_, hi_, 0, 1, 2, 3, 4, 5, 6, 7);                 \
        }                                                                                       \
        _Pragma("unroll")                                                                       \
        for (int ni = 0; ni < 2; ni++) {                                                        \
            i32x4 lo_ = *(const i32x4*)(baB + rowBby + ni * 2048 + cA0);                        \
            i32x4 hi_ = *(const i32x4*)(baB + rowBby + ni * 2048 + cA1);                        \
            bfr[ni] = __builtin_shufflevector(lo_, hi_, 0, 1, 2, 3, 4, 5, 6, 7);                \
        }                                                                                       \
        if (dostage_) STAGE_REGION((p_) + 1);                                                   \
        __builtin_amdgcn_s_setprio(1);                                                          \
        _Pragma("unroll")                                                                       \
        for (int mi = 0; mi < 4; mi++)                                                          \
            _Pragma("unroll")                                                                   \
            for (int ni = 0; ni < 2; ni++)                                                      \
                acc[mi][ni] = __builtin_amdgcn_mfma_scale_f32_16x16x128_f8f6f4(                 \
                    af[mi], bfr[ni], acc[mi][ni], 0, 0,                                         \
                    0, 0x7F7F7F7F, 0, 0x7F7F7F7F);                                              \
        __builtin_amdgcn_s_setprio(0);                                                          \
        VMW(0);                                                                                 \
        __builtin_amdgcn_s_barrier();                                                           \
    }

    PHASE(0, 1);
    PHASE(1, 1);
    PHASE(2, 1);
    PHASE(3, 0);

#undef PHASE
#undef STAGE_REGION
#undef VMW

    // stage per-row/col metadata for the epilogue
    if (t < 128) {
        const int gi = b * NPT + tm * 128 + t;
        s_sqr[t]   = sq[gi];
        s_mr[t]    = mask[gi];
        s_cr[t][0] = coords[(size_t)gi * 3 + 0];
        s_cr[t][1] = coords[(size_t)gi * 3 + 1];
        s_cr[t][2] = coords[(size_t)gi * 3 + 2];
    } else if (t < 256) {
        const int rr = t - 128;
        const int gi = b * NPT + tn * 128 + rr;
        s_sqc[rr]   = sq[gi];
        s_mc[rr]    = mask[gi];
        s_cc[rr][0] = coords[(size_t)gi * 3 + 0];
        s_cc[rr][1] = coords[(size_t)gi * 3 + 1];
        s_cc[rr][2] = coords[(size_t)gi * 3 + 2];
    }
    __syncthreads();

    // C/D layout (shape-determined): col = lane&15, row = (lane>>4)*4 + reg
    float lsum = 0.f;
#pragma unroll
    for (int mi = 0; mi < 4; mi++) {
#pragma unroll
        for (int j = 0; j < 4; j++) {
            const int rl  = wr * 64 + mi * 16 + lhi * 4 + j;
            const float sqr = s_sqr[rl];
            const float mr  = s_mr[rl];
            const float cx = s_cr[rl][0], cy = s_cr[rl][1], cz = s_cr[rl][2];
#pragma unroll
            for (int ni = 0; ni < 2; ni++) {
                const int cl = wc * 32 + ni * 16 + llo;
                const float g  = acc[mi][ni][j];
                float d2 = sqr + s_sqc[cl] - 2.f * g;
                d2 = fmaxf(d2, 0.f);
                const float de = sqrtf(d2);
                const float lo = fmaxf(de - 1.0f, 0.f);
                const float dx = cx - s_cc[cl][0];
                const float dy = cy - s_cc[cl][1];
                const float dz = cz - s_cc[cl][2];
                const float cd2 = dx*dx + dy*dy + dz*dz;
                const float wgt = (cd2 < 100.0f) ? mr * s_mc[cl] : 0.f;
                lsum += lo * wgt;
            }
        }
    }
    // off-diagonal tiles stand for both (tm,tn) and (tn,tm)
    if (tm != tn) lsum *= 2.0f;

#pragma unroll
    for (int o = 32; o; o >>= 1) lsum += __shfl_xor(lsum, o);
    if (lane == 0) s_wsum[wave] = lsum;
    __syncthreads();
    if (t == 0) {
        float bs = 0.f;
#pragma unroll
        for (int i = 0; i < 8; i++) bs += s_wsum[i];
        partials[bid] = bs;
    }
}

// ---------------- kernel 4: final deterministic reduce ----------------
__global__ __launch_bounds__(256) void finalize_kernel(const float* __restrict__ partials,
                                                       const float* __restrict__ msum,
                                                       float* __restrict__ out) {
    double s = 0.0;
    for (int i = threadIdx.x; i < NBLK; i += 256) s += (double)partials[i];
#pragma unroll
    for (int o = 32; o; o >>= 1) s += __shfl_xor(s, o);
    __shared__ double ws[4];
    if ((threadIdx.x & 63) == 0) ws[threadIdx.x >> 6] = s;
    __syncthreads();
    if (threadIdx.x == 0) {
        const double tot = ws[0] + ws[1] + ws[2] + ws[3];
        double valid = 0.0;
        for (int bb = 0; bb < BATCH; bb++) valid += (double)msum[bb] * (double)msum[bb];
        out[0] = (float)(tot / (valid + 1e-8));
    }
}

extern "C" void kernel_launch(void* const* d_in, const int* in_sizes, int n_in,
                              void* d_out, int out_size, void* d_ws, size_t ws_size,
                              hipStream_t stream) {
    const float* emb    = (const float*)d_in[0];
    const float* coords = (const float*)d_in[1];
    const float* mask   = (const float*)d_in[2];

    char* ws = (char*)d_ws;
    unsigned char* xn  = (unsigned char*)ws;
    float* sq          = (float*)(ws + OFF_SQ);
    float* msum        = (float*)(ws + OFF_MSUM);
    float* partials    = (float*)(ws + OFF_PARTIALS);
    float* out         = (float*)d_out;

    normalize_kernel<<<dim3(BATCH * NPT / 4), dim3(256), 0, stream>>>(emb, xn, sq);
    masksum_kernel<<<dim3(BATCH), dim3(256), 0, stream>>>(mask, msum);
    gram_loss_kernel<<<dim3(NBLK), dim3(512), 0, stream>>>(xn, sq, coords, mask, partials);
    finalize_kernel<<<dim3(1), dim3(256), 0, stream>>>(partials, msum, out);
}

// Round 21
// 56.693 us; speedup vs baseline: 2.3695x; 2.3695x over previous
//
#include <hip/hip_runtime.h>
#include <hip/hip_bf16.h>

#define BATCH 8
#define NPT   2048
#define DIM   512
#define NTILE 16            // 2048/128 tiles per dim
#define NTRI  136           // 16*17/2 symmetric tiles per batch
#define NBLK  (NTRI * BATCH) // 1088

typedef __attribute__((ext_vector_type(4))) float f32x4;

// ---------------- workspace layout ----------------
// xn (fp8)  : 8,388,608 B at 0
#define OFF_SQ       16777216
#define OFF_MSUM     16842752
#define OFF_PARTIALS 16842784   // 1088 floats

// ---------------- kernel 1: normalize rows, emit fp8 e4m3 + per-row |x_q|^2 ----------------
__global__ __launch_bounds__(256) void normalize_kernel(const float* __restrict__ emb,
                                                        unsigned char* __restrict__ xn,
                                                        float* __restrict__ sq) {
    const int wave = threadIdx.x >> 6;
    const int lane = threadIdx.x & 63;
    const int row  = blockIdx.x * 4 + wave;

    const float4* src = (const float4*)(emb + (size_t)row * DIM);
    float4 v0 = src[lane * 2 + 0];
    float4 v1 = src[lane * 2 + 1];

    float ss = v0.x*v0.x + v0.y*v0.y + v0.z*v0.z + v0.w*v0.w
             + v1.x*v1.x + v1.y*v1.y + v1.z*v1.z + v1.w*v1.w;
#pragma unroll
    for (int o = 32; o; o >>= 1) ss += __shfl_xor(ss, o);

    const float inv = 1.0f / fmaxf(sqrtf(ss), 1e-12f);

    const float f0 = v0.x*inv, f1 = v0.y*inv, f2 = v0.z*inv, f3 = v0.w*inv;
    const float f4 = v1.x*inv, f5 = v1.y*inv, f6 = v1.z*inv, f7 = v1.w*inv;

    int lo = __builtin_amdgcn_cvt_pk_fp8_f32(f0, f1, 0, 0);
    lo     = __builtin_amdgcn_cvt_pk_fp8_f32(f2, f3, lo, 1);
    int hi = __builtin_amdgcn_cvt_pk_fp8_f32(f4, f5, 0, 0);
    hi     = __builtin_amdgcn_cvt_pk_fp8_f32(f6, f7, hi, 1);

    float s2 = 0.f;
    {
        float a;
        a = __builtin_amdgcn_cvt_f32_fp8(lo, 0); s2 += a * a;
        a = __builtin_amdgcn_cvt_f32_fp8(lo, 1); s2 += a * a;
        a = __builtin_amdgcn_cvt_f32_fp8(lo, 2); s2 += a * a;
        a = __builtin_amdgcn_cvt_f32_fp8(lo, 3); s2 += a * a;
        a = __builtin_amdgcn_cvt_f32_fp8(hi, 0); s2 += a * a;
        a = __builtin_amdgcn_cvt_f32_fp8(hi, 1); s2 += a * a;
        a = __builtin_amdgcn_cvt_f32_fp8(hi, 2); s2 += a * a;
        a = __builtin_amdgcn_cvt_f32_fp8(hi, 3); s2 += a * a;
    }

    uint2 pk; pk.x = (unsigned)lo; pk.y = (unsigned)hi;
    *(uint2*)(xn + (size_t)row * DIM + lane * 8) = pk;

#pragma unroll
    for (int o = 32; o; o >>= 1) s2 += __shfl_xor(s2, o);
    if (lane == 0) sq[row] = s2;
}

// ---------------- kernel 2: per-batch mask sums (8 parallel blocks) ----------------
// NOTE round 16: fusing this into finalize (serial 8-batch loop in one block)
// cost 13 us. Keep it as an 8-block parallel kernel.
__global__ __launch_bounds__(256) void masksum_kernel(const float* __restrict__ mask,
                                                      float* __restrict__ msum) {
    const int b = blockIdx.x;
    float s = 0.f;
    for (int i = threadIdx.x; i < NPT; i += 256) s += mask[b * NPT + i];
#pragma unroll
    for (int o = 32; o; o >>= 1) s += __shfl_xor(s, o);
    __shared__ float ws[4];
    if ((threadIdx.x & 63) == 0) ws[threadIdx.x >> 6] = s;
    __syncthreads();
    if (threadIdx.x == 0) msum[b] = ws[0] + ws[1] + ws[2] + ws[3];
}

// ---------------- kernel 3: fp8 Gram, 128x128 tile, 8 waves x (64x32), BK=32 ----------------
// FINAL structure (rounds 12/17/19 optimum; 13 structural variants bracket
// 290-365 TF, this is the measured best at 56.2 us total). 4-region rotation
// (4 KB/side/region), stage 3 ahead, counted VMW(2), 1 barrier/phase.
// Staging: 1 gload_lds/thread/region (waves 0-3 A, 4-7 B). Swizzle: stored
// 16-B chunk c holds source chunk c ^ ((row>>2)&1); read octet =
// lhi ^ ((llo>>2)&2) -> 2-way bank aliasing (free per m136).
// Proven-infeasible alternatives: 256^2 spills w/ bf16 (r2-4) AND fp8 (r18);
// 256x128 spills (r15); MX K=128 operands spill via scratch (r20: FETCH 159 MB);
// whole-panel loses co-residency (r13); 4 blk/CU thrashes L2 (r14);
// masksum fusion serializes (r16).
__global__ __launch_bounds__(512, 4) void gram_loss_kernel(const unsigned char* __restrict__ xn,
                                                           const float* __restrict__ sq,
                                                           const float* __restrict__ coords,
                                                           const float* __restrict__ mask,
                                                           float* __restrict__ partials) {
    __shared__ __align__(16) unsigned char ldsA[4][4096];   // 16 KB
    __shared__ __align__(16) unsigned char ldsB[4][4096];   // 16 KB
    __shared__ float s_sqr[128], s_sqc[128], s_mr[128], s_mc[128];
    __shared__ float s_cr[128][3], s_cc[128][3];
    __shared__ float s_wsum[8];

    // XCD-chunked: 1088 = 8 * 136; batch == XCD id -> ~1 MB panel set per XCD L2
    const int bid = blockIdx.x;
    const int b   = bid & 7;
    int r = bid >> 3;
    int tm = 0;
    while (r >= NTILE - tm) { r -= NTILE - tm; tm++; }
    const int tn = tm + r;

    const int t    = threadIdx.x;
    const int wave = t >> 6, lane = t & 63;
    const int wr = wave >> 2, wc = wave & 3;      // 2 x 4 wave grid: 64-row x 32-col tiles
    const int lhi = lane >> 4, llo = lane & 15;

    const size_t rowBaseA = (size_t)(b * NPT + tm * 128);
    const size_t rowBaseB = (size_t)(b * NPT + tn * 128);

    f32x4 acc[4][2];
#pragma unroll
    for (int i = 0; i < 4; i++)
#pragma unroll
        for (int j = 0; j < 2; j++) acc[i][j] = (f32x4){0.f, 0.f, 0.f, 0.f};

    // staging: region = 128 rows x 32 k fp8 = 4 KB/side = 256 lanes x 16 B.
    // thread t: side = t>=256; l = t&255; row = l>>1; chunk = l&1;
    // source chunk pre-swizzled: (l&1) ^ ((row>>2)&1) -> byte ((2*(l&1))^((l>>3)&2))*8.
    const int ls    = t & 255;
    const int side  = t >> 8;                 // 0 = A (waves 0-3), 1 = B (waves 4-7)
    const int srow  = ls >> 1;
    const int scolB = ((2 * (ls & 1)) ^ ((ls >> 3) & 2)) * 8;

    const unsigned char* gsrc = xn + ((side ? rowBaseB : rowBaseA) + (size_t)srow) * DIM + scolB;
    const int dstoff = ls * 16;

#define STAGE_REGION(q_)                                                                        \
    {                                                                                           \
        unsigned char* d_ = (side ? &ldsB[(q_) & 3][0] : &ldsA[(q_) & 3][0]) + dstoff;          \
        __builtin_amdgcn_global_load_lds(                                                       \
            (const __attribute__((address_space(1))) void*)(gsrc + (q_) * 32),                  \
            (__attribute__((address_space(3))) void*)d_, 16, 0, 0);                             \
    }

#define VMW(n_) asm volatile("s_waitcnt vmcnt(" #n_ ")" ::: "memory")

    // prologue: regions 0,1,2 in flight (1 load/thread each)
    STAGE_REGION(0);
    STAGE_REGION(1);
    STAGE_REGION(2);

    // read: byte = row*32 + (lhi ^ ((llo>>2)&2))*8
    const int koff   = (lhi ^ ((llo >> 2) & 2)) * 8;
    const int rowAby = (wr * 64 + llo) * 32;   // + mi*512
    const int rowBby = (wc * 32 + llo) * 32;   // + ni*512

#pragma unroll 1
    for (int p = 0; p < 16; p++) {
        if (p < 14)      { VMW(2); }
        else if (p == 14){ VMW(1); }
        else             { VMW(0); }
        __builtin_amdgcn_s_barrier();

        const unsigned char* baA = &ldsA[p & 3][0];
        const unsigned char* baB = &ldsB[p & 3][0];
        long af[4], bfr[2];
#pragma unroll
        for (int mi = 0; mi < 4; mi++)
            af[mi] = *(const long*)(baA + rowAby + mi * 512 + koff);
#pragma unroll
        for (int ni = 0; ni < 2; ni++)
            bfr[ni] = *(const long*)(baB + rowBby + ni * 512 + koff);

        if (p < 13) STAGE_REGION(p + 3);

        __builtin_amdgcn_s_setprio(1);
#pragma unroll
        for (int mi = 0; mi < 4; mi++)
#pragma unroll
            for (int ni = 0; ni < 2; ni++)
                acc[mi][ni] = __builtin_amdgcn_mfma_f32_16x16x32_fp8_fp8(af[mi], bfr[ni],
                                                                         acc[mi][ni], 0, 0, 0);
        __builtin_amdgcn_s_setprio(0);
    }

#undef STAGE_REGION
#undef VMW

    // stage per-row/col metadata for the epilogue
    __syncthreads();
    if (t < 128) {
        const int gi = b * NPT + tm * 128 + t;
        s_sqr[t]   = sq[gi];
        s_mr[t]    = mask[gi];
        s_cr[t][0] = coords[(size_t)gi * 3 + 0];
        s_cr[t][1] = coords[(size_t)gi * 3 + 1];
        s_cr[t][2] = coords[(size_t)gi * 3 + 2];
    } else if (t < 256) {
        const int rr = t - 128;
        const int gi = b * NPT + tn * 128 + rr;
        s_sqc[rr]   = sq[gi];
        s_mc[rr]    = mask[gi];
        s_cc[rr][0] = coords[(size_t)gi * 3 + 0];
        s_cc[rr][1] = coords[(size_t)gi * 3 + 1];
        s_cc[rr][2] = coords[(size_t)gi * 3 + 2];
    }
    __syncthreads();

    // C/D layout: col = lane&15, row = (lane>>4)*4 + reg
    float lsum = 0.f;
#pragma unroll
    for (int mi = 0; mi < 4; mi++) {
#pragma unroll
        for (int j = 0; j < 4; j++) {
            const int rl  = wr * 64 + mi * 16 + lhi * 4 + j;
            const float sqr = s_sqr[rl];
            const float mr  = s_mr[rl];
            const float cx = s_cr[rl][0], cy = s_cr[rl][1], cz = s_cr[rl][2];
#pragma unroll
            for (int ni = 0; ni < 2; ni++) {
                const int cl = wc * 32 + ni * 16 + llo;
                const float g  = acc[mi][ni][j];
                float d2 = sqr + s_sqc[cl] - 2.f * g;
                d2 = fmaxf(d2, 0.f);
                const float de = sqrtf(d2);
                const float lo = fmaxf(de - 1.0f, 0.f);
                const float dx = cx - s_cc[cl][0];
                const float dy = cy - s_cc[cl][1];
                const float dz = cz - s_cc[cl][2];
                const float cd2 = dx*dx + dy*dy + dz*dz;
                const float wgt = (cd2 < 100.0f) ? mr * s_mc[cl] : 0.f;
                lsum += lo * wgt;
            }
        }
    }
    // off-diagonal tiles stand for both (tm,tn) and (tn,tm)
    if (tm != tn) lsum *= 2.0f;

#pragma unroll
    for (int o = 32; o; o >>= 1) lsum += __shfl_xor(lsum, o);
    if (lane == 0) s_wsum[wave] = lsum;
    __syncthreads();
    if (t == 0) {
        float bs = 0.f;
#pragma unroll
        for (int i = 0; i < 8; i++) bs += s_wsum[i];
        partials[bid] = bs;
    }
}

// ---------------- kernel 4: final deterministic reduce ----------------
__global__ __launch_bounds__(256) void finalize_kernel(const float* __restrict__ partials,
                                                       const float* __restrict__ msum,
                                                       float* __restrict__ out) {
    double s = 0.0;
    for (int i = threadIdx.x; i < NBLK; i += 256) s += (double)partials[i];
#pragma unroll
    for (int o = 32; o; o >>= 1) s += __shfl_xor(s, o);
    __shared__ double ws[4];
    if ((threadIdx.x & 63) == 0) ws[threadIdx.x >> 6] = s;
    __syncthreads();
    if (threadIdx.x == 0) {
        const double tot = ws[0] + ws[1] + ws[2] + ws[3];
        double valid = 0.0;
        for (int bb = 0; bb < BATCH; bb++) valid += (double)msum[bb] * (double)msum[bb];
        out[0] = (float)(tot / (valid + 1e-8));
    }
}

extern "C" void kernel_launch(void* const* d_in, const int* in_sizes, int n_in,
                              void* d_out, int out_size, void* d_ws, size_t ws_size,
                              hipStream_t stream) {
    const float* emb    = (const float*)d_in[0];
    const float* coords = (const float*)d_in[1];
    const float* mask   = (const float*)d_in[2];

    char* ws = (char*)d_ws;
    unsigned char* xn  = (unsigned char*)ws;
    float* sq          = (float*)(ws + OFF_SQ);
    float* msum        = (float*)(ws + OFF_MSUM);
    float* partials    = (float*)(ws + OFF_PARTIALS);
    float* out         = (float*)d_out;

    normalize_kernel<<<dim3(BATCH * NPT / 4), dim3(256), 0, stream>>>(emb, xn, sq);
    masksum_kernel<<<dim3(BATCH), dim3(256), 0, stream>>>(mask, msum);
    gram_loss_kernel<<<dim3(NBLK), dim3(512), 0, stream>>>(xn, sq, coords, mask, partials);
    finalize_kernel<<<dim3(1), dim3(256), 0, stream>>>(partials, msum, out);
}